// Round 3
// baseline (146.922 us; speedup 1.0000x reference)
//
#include <hip/hip_runtime.h>
#include <hip/hip_bf16.h>

// Problem: B=4, L=2048, D_MODEL=1024, H=16, D_QKV=64.
// Reference einsum 'bhlk,blhd->blhd' contracts k over logits only; softmax sums to 1,
// so attention output == v and the net reduces to:
//   out = x @ Wc + fc_b,  Wc[m][j] = sum_{hd} w_v[h][m][d] * fc_w[j][hd]
// Two launches (NO grid barrier — per-XCD L2 non-coherence makes spin barriers cost ~250us):
//   prep: blocks 0-255 fold Wc^T (LDS-staged, double-buffered, XOR-swizzled mini-GEMM)
//         || blocks 256-1023 cast x->bf16 (grid-stride, independent)
//   final_gemm: 128x64-tile GEMM, 1024 blocks.
// Round-0: prep rewrite (41.5us -> ~20us measured via total 151->133.5).
// Round-2: final_gemm was the stage->wait->compute structure (zero load/compute overlap,
// MfmaUtil ~9%). Rewritten as the documented "minimum 2-phase" pipeline (T3): LDS dbuf
// 48KB, stage tile t+1 BEFORE computing tile t, ONE barrier per K-step — loads stay in
// flight under the 12 ds_reads + 16 MFMAs. Plus XCD-bijective swizzle (1024%8==0) so the
// 16 N-blocks sharing an A M-tile live on one XCD's L2. Accumulation order unchanged.

typedef __attribute__((ext_vector_type(8))) short bf16x8;
typedef __attribute__((ext_vector_type(4))) float f32x4;

__device__ __forceinline__ f32x4 mfma16(bf16x8 a, bf16x8 b, f32x4 c) {
  return __builtin_amdgcn_mfma_f32_16x16x32_bf16(a, b, c, 0, 0, 0);
}

// fp32 -> bf16 bits, round-to-nearest-even
__device__ __forceinline__ unsigned short f2b(float f) {
  unsigned int u = __builtin_bit_cast(unsigned int, f);
  return (unsigned short)((u + 0x7fffu + ((u >> 16) & 1u)) >> 16);
}

__device__ __forceinline__ bf16x8 cvt8(float4 a, float4 b) {
  bf16x8 r;
  r[0] = (short)f2b(a.x); r[1] = (short)f2b(a.y); r[2] = (short)f2b(a.z); r[3] = (short)f2b(a.w);
  r[4] = (short)f2b(b.x); r[5] = (short)f2b(b.y); r[6] = (short)f2b(b.z); r[7] = (short)f2b(b.w);
  return r;
}

// async global->LDS, 16 B per lane (m97 pattern; LDS dest = wave-uniform base + lane*16)
__device__ __forceinline__ void gld_lds16(const void* g, void* l) {
  __builtin_amdgcn_global_load_lds((const __attribute__((address_space(1))) unsigned int*)g,
                                   (__attribute__((address_space(3))) unsigned int*)l, 16, 0, 0);
}

// prep: blocks 0-255 fold Wc^T; blocks 256-1023 cast x->bf16. No inter-block dependency.
__global__ __launch_bounds__(256) void prep(const float* __restrict__ x,
                                            const float* __restrict__ wv,
                                            const float* __restrict__ fcw,
                                            unsigned short* __restrict__ xb,
                                            unsigned short* __restrict__ wcT) {
  // Fold LDS: per-h 64x64 bf16 slabs of A=fcw[j][k] and B=wv-as-[m][d], double-buffered.
  // 32 KB total. XOR swizzle (row&7)<<4 on the in-row byte so the stride-128B fragment
  // reads are <=2-way bank aliases (free) instead of 16-way.
  __shared__ __align__(16) short As[2][64 * 64];
  __shared__ __align__(16) short Bs[2][64 * 64];

  int bid = blockIdx.x, t = threadIdx.x;
  int wid = t >> 6, lane = t & 63, l16 = lane & 15, quad = lane >> 4;

  if (bid < 256) {
    // wcT[j][m] = sum_{h,d} fcw[j][h*64+d] * wv[h][m][d]; 64x64 output tile, 4 waves 2x2,
    // each wave a 32x32 sub-tile (2x2 frags of 16x16), K-loop = 16 h-slabs of 64.
    int j0 = (bid >> 4) * 64;   // j tile
    int m0 = (bid & 15) * 64;   // m tile
    int wr = wid >> 1, wc = wid & 1;
    int rowt = t >> 3, colb = (t & 7) * 8;  // staging: chunk c row = c*32+rowt, 8 floats at colb

    f32x4 acc[2][2];
#pragma unroll
    for (int a = 0; a < 2; a++)
#pragma unroll
      for (int b = 0; b < 2; b++) acc[a][b] = (f32x4){0.f, 0.f, 0.f, 0.f};

    float4 ra[2][2], rb[2][2];  // [chunk][2xfloat4] in-flight slab

#define LOADH(h)                                                                     \
    {                                                                                \
      _Pragma("unroll")                                                              \
      for (int c = 0; c < 2; c++) {                                                  \
        int row = c * 32 + rowt;                                                     \
        const float* pa = fcw + (j0 + row) * 1024 + (h) * 64 + colb;                 \
        ra[c][0] = *reinterpret_cast<const float4*>(pa);                             \
        ra[c][1] = *reinterpret_cast<const float4*>(pa + 4);                         \
        const float* pb = wv + (h) * 65536 + (m0 + row) * 64 + colb;                 \
        rb[c][0] = *reinterpret_cast<const float4*>(pb);                             \
        rb[c][1] = *reinterpret_cast<const float4*>(pb + 4);                         \
      }                                                                              \
    }
#define STOREH(buf)                                                                  \
    {                                                                                \
      _Pragma("unroll")                                                              \
      for (int c = 0; c < 2; c++) {                                                  \
        int row = c * 32 + rowt;                                                     \
        int bo = row * 128 + ((colb * 2) ^ ((row & 7) << 4));                        \
        *reinterpret_cast<bf16x8*>((char*)As[buf] + bo) = cvt8(ra[c][0], ra[c][1]);  \
        *reinterpret_cast<bf16x8*>((char*)Bs[buf] + bo) = cvt8(rb[c][0], rb[c][1]);  \
      }                                                                              \
    }

    LOADH(0);
    STOREH(0);
    __syncthreads();

    for (int h = 0; h < 16; ++h) {
      int cur = h & 1;
      if (h < 15) LOADH(h + 1);  // issue-early: HBM latency hides under frag reads + MFMA

      bf16x8 af[2][2], bg[2][2];  // [tile][ks]
#pragma unroll
      for (int rt = 0; rt < 2; rt++) {
        int rowf = wr * 32 + rt * 16 + l16;
        int rbase = rowf * 128, rx = (rowf & 7) << 4;
        af[rt][0] = *reinterpret_cast<const bf16x8*>((char*)As[cur] + rbase + ((quad * 16) ^ rx));
        af[rt][1] = *reinterpret_cast<const bf16x8*>((char*)As[cur] + rbase + ((64 + quad * 16) ^ rx));
      }
#pragma unroll
      for (int ct = 0; ct < 2; ct++) {
        int rowf = wc * 32 + ct * 16 + l16;
        int rbase = rowf * 128, rx = (rowf & 7) << 4;
        bg[ct][0] = *reinterpret_cast<const bf16x8*>((char*)Bs[cur] + rbase + ((quad * 16) ^ rx));
        bg[ct][1] = *reinterpret_cast<const bf16x8*>((char*)Bs[cur] + rbase + ((64 + quad * 16) ^ rx));
      }
#pragma unroll
      for (int ks = 0; ks < 2; ks++)
#pragma unroll
        for (int rt = 0; rt < 2; rt++)
#pragma unroll
          for (int ct = 0; ct < 2; ct++)
            acc[rt][ct] = mfma16(af[rt][ks], bg[ct][ks], acc[rt][ct]);

      if (h < 15) STOREH(cur ^ 1);  // write-late into the other buffer
      __syncthreads();
    }
#undef LOADH
#undef STOREH

#pragma unroll
    for (int rt = 0; rt < 2; rt++)
#pragma unroll
      for (int ct = 0; ct < 2; ct++) {
        int jj = j0 + wr * 32 + rt * 16 + quad * 4;
        int mm = m0 + wc * 32 + ct * 16 + l16;
#pragma unroll
        for (int r = 0; r < 4; r++) wcT[(jj + r) * 1024 + mm] = f2b(acc[rt][ct][r]);
      }
  } else {
    // cast: x fp32 -> bf16. 8.4M elems = 4096 chunks of 2048; 768 blocks grid-stride
    // (~5.3 chunks each) so HBM latency is hidden by TLP (4 blocks/CU overall grid).
    int cb = bid - 256;
    for (int ch = cb; ch < 4096; ch += 768) {
      int idx = ch * 2048 + t * 8;
      float4 a = *reinterpret_cast<const float4*>(x + idx);
      float4 b = *reinterpret_cast<const float4*>(x + idx + 4);
      *reinterpret_cast<bf16x8*>(xb + idx) = cvt8(a, b);
    }
  }
}

// out[i][j] = sum_m xb[i][m]*wcT[j][m] + fcb[j].  M=8192,N=1024,K=1024.
// 128x64 tile, BK=64 (two 32-k slabs), 1024 blocks N-fastest.
// Round-2: 2-phase pipeline — LDS double-buffered (48KB, 3 blocks/CU), stage tile t+1
// BEFORE computing tile t, ONE __syncthreads per K-step (its implied vmcnt(0) is the
// pipeline wait). XCD-bijective swizzle: each XCD owns 128 consecutive tiles = 8 complete
// M-rows so the 16 N-blocks sharing an A M-tile hit one L2.
__global__ __launch_bounds__(256, 3) void final_gemm(const unsigned short* __restrict__ xb,
                                                     const unsigned short* __restrict__ wcT,
                                                     const float* __restrict__ fcb,
                                                     float* __restrict__ out) {
  __shared__ __align__(16) unsigned short As[2][128 * 64];  // 32 KB  [buf][slab][row][32]
  __shared__ __align__(16) unsigned short Bs[2][64 * 64];   // 16 KB
  int t = threadIdx.x, wid = t >> 6, lane = t & 63, l16 = lane & 15, quad = lane >> 4;
  int wr = wid >> 1, wc = wid & 1;
  int swz = (blockIdx.x & 7) * 128 + (blockIdx.x >> 3);  // bijective: 1024 % 8 == 0
  int row0 = (swz >> 4) * 128;   // M tile (64)
  int col0 = (swz & 15) * 64;    // N tile (16) — fastest within an XCD chunk

  // A staging: 16 x 1KB chunks/buf; blk = wid*4+j: slab blk>>3, rows (blk&7)*16+lane>>2, kq lane&3.
  // B staging:  8 x 1KB chunks/buf; blk = wid*2+j: slab blk>>2, rows (blk&3)*16+lane>>2, kq lane&3.
  int w4 = wid * 4, w2 = wid * 2;
  const unsigned short* Ap[4];
  const unsigned short* Bp[2];
#pragma unroll
  for (int j = 0; j < 4; j++) {
    int blk = w4 + j, s = blk >> 3;
    int row = (blk & 7) * 16 + (lane >> 2), kq = lane & 3;
    Ap[j] = xb + (row0 + row) * 1024 + s * 32 + kq * 8;
  }
#pragma unroll
  for (int j = 0; j < 2; j++) {
    int blk = w2 + j, s = blk >> 2;
    int row = (blk & 3) * 16 + (lane >> 2), kq = lane & 3;
    Bp[j] = wcT + (col0 + row) * 1024 + s * 32 + kq * 8;
  }

  f32x4 acc[4][2];
#pragma unroll
  for (int rt = 0; rt < 4; rt++)
#pragma unroll
    for (int ct = 0; ct < 2; ct++) acc[rt][ct] = (f32x4){0.f, 0.f, 0.f, 0.f};

  // prologue: stage tile 0 into buf 0
#pragma unroll
  for (int j = 0; j < 4; j++) gld_lds16(Ap[j], &As[0][(w4 + j) * 512 + lane * 8]);
#pragma unroll
  for (int j = 0; j < 2; j++) gld_lds16(Bp[j], &Bs[0][(w2 + j) * 512 + lane * 8]);
  __syncthreads();  // implied vmcnt(0): buf0 ready

  for (int tk = 0; tk < 16; ++tk) {
    int cur = tk & 1;
    if (tk < 15) {  // issue next-tile stage FIRST — in flight under ds_reads + MFMAs
      int k0 = (tk + 1) * 64;
#pragma unroll
      for (int j = 0; j < 4; j++) gld_lds16(Ap[j] + k0, &As[cur ^ 1][(w4 + j) * 512 + lane * 8]);
#pragma unroll
      for (int j = 0; j < 2; j++) gld_lds16(Bp[j] + k0, &Bs[cur ^ 1][(w2 + j) * 512 + lane * 8]);
    }
#pragma unroll
    for (int s = 0; s < 2; s++) {
      bf16x8 af[4], bfr[2];
#pragma unroll
      for (int rt = 0; rt < 4; rt++)
        af[rt] = *reinterpret_cast<const bf16x8*>(&As[cur][s * 4096 + (wr * 64 + rt * 16 + l16) * 32 + quad * 8]);
#pragma unroll
      for (int ct = 0; ct < 2; ct++)
        bfr[ct] = *reinterpret_cast<const bf16x8*>(&Bs[cur][s * 2048 + (wc * 32 + ct * 16 + l16) * 32 + quad * 8]);
#pragma unroll
      for (int rt = 0; rt < 4; rt++)
#pragma unroll
        for (int ct = 0; ct < 2; ct++)
          acc[rt][ct] = mfma16(af[rt], bfr[ct], acc[rt][ct]);
    }
    __syncthreads();  // drains vmcnt (next buf staged) + all waves done reading cur
  }

#pragma unroll
  for (int ct = 0; ct < 2; ct++) {
    int j = col0 + wc * 32 + ct * 16 + l16;
    float bias = fcb[j];
#pragma unroll
    for (int rt = 0; rt < 4; rt++) {
      int i0 = row0 + wr * 64 + rt * 16 + quad * 4;
      f32x4 a = acc[rt][ct];
#pragma unroll
      for (int r = 0; r < 4; r++) out[(i0 + r) * 1024 + j] = a[r] + bias;
    }
  }
}

extern "C" void kernel_launch(void* const* d_in, const int* in_sizes, int n_in,
                              void* d_out, int out_size, void* d_ws, size_t ws_size,
                              hipStream_t stream) {
  const float* x   = (const float*)d_in[0];
  // d_in[1] mask, d_in[2] w_q, d_in[3] w_k: dead per reference semantics
  const float* wv  = (const float*)d_in[4];
  const float* fcw = (const float*)d_in[5];
  const float* fcb = (const float*)d_in[6];
  float* out = (float*)d_out;

  char* ws = (char*)d_ws;
  unsigned short* xb  = (unsigned short*)(ws);              // 16 MB (8192x1024 bf16)
  unsigned short* wcT = (unsigned short*)(ws + 16777216);   // 2 MB  (1024x1024 bf16)

  prep<<<1024, 256, 0, stream>>>(x, wv, fcw, xb, wcT);
  final_gemm<<<1024, 256, 0, stream>>>(xb, wcT, fcb, out);
}

// Round 6
// 139.669 us; speedup vs baseline: 1.0519x; 1.0519x over previous
//
#include <hip/hip_runtime.h>
#include <hip/hip_bf16.h>

// Problem: B=4, L=2048, D_MODEL=1024, H=16, D_QKV=64.
// Reference einsum 'bhlk,blhd->blhd' contracts k over logits only; softmax sums to 1,
// so attention output == v and the net reduces to:
//   out = x @ Wc + fc_b,  Wc[m][j] = sum_{hd} w_v[h][m][d] * fc_w[j][hd]
// Two launches:
//   prep: blocks 0-255 fold Wc^T || blocks 256-1023 cast x->bf16.
//   final_gemm: 128x64-tile GEMM, 1024 blocks, 4 blocks/CU, counted-vmcnt pipeline.
// Round-0: prep rewrite (41.5us -> ~15-20us; total 151->133.5).
// Round-3: 1-deep dbuf + 3 blk/CU REGRESSED (146.9): compute phase too short, lost TLP.
// Round-4 FAILED (wrong output): counted-vmcnt pipeline used RAW s_barrier with no
//   compiler memory fence -> (a) ds_reads hoistable above the barrier (vmcnt(3) only
//   proves MY wave's chunks landed; other waves' need the barrier), (b) wave can cross
//   barrier with ds_reads still queued -> STAGE(t+2) WAR-races them.
// Round-5 fix (matches m201/m218 template discipline): per iter
//   s_waitcnt vmcnt(3) lgkmcnt(0) [mem-clobber asm] ; sched_barrier ; s_barrier ;
//   empty mem-clobber asm ; sched_barrier ; STAGE(t+2) ; COMPUTE(t).
//   Round-5 bench died on container acquisition (infra, same signature as round 1);
//   audit found no fault/hang path (uniform barriers, exact vmcnt invariant, in-bounds).
//   Round-6: identical resubmit.

typedef __attribute__((ext_vector_type(8))) short bf16x8;
typedef __attribute__((ext_vector_type(4))) float f32x4;

__device__ __forceinline__ f32x4 mfma16(bf16x8 a, bf16x8 b, f32x4 c) {
  return __builtin_amdgcn_mfma_f32_16x16x32_bf16(a, b, c, 0, 0, 0);
}

// fp32 -> bf16 bits, round-to-nearest-even
__device__ __forceinline__ unsigned short f2b(float f) {
  unsigned int u = __builtin_bit_cast(unsigned int, f);
  return (unsigned short)((u + 0x7fffu + ((u >> 16) & 1u)) >> 16);
}

__device__ __forceinline__ bf16x8 cvt8(float4 a, float4 b) {
  bf16x8 r;
  r[0] = (short)f2b(a.x); r[1] = (short)f2b(a.y); r[2] = (short)f2b(a.z); r[3] = (short)f2b(a.w);
  r[4] = (short)f2b(b.x); r[5] = (short)f2b(b.y); r[6] = (short)f2b(b.z); r[7] = (short)f2b(b.w);
  return r;
}

// async global->LDS, 16 B per lane (m97 pattern; LDS dest = wave-uniform base + lane*16)
__device__ __forceinline__ void gld_lds16(const void* g, void* l) {
  __builtin_amdgcn_global_load_lds((const __attribute__((address_space(1))) unsigned int*)g,
                                   (__attribute__((address_space(3))) unsigned int*)l, 16, 0, 0);
}

// prep: blocks 0-255 fold Wc^T; blocks 256-1023 cast x->bf16. No inter-block dependency.
__global__ __launch_bounds__(256) void prep(const float* __restrict__ x,
                                            const float* __restrict__ wv,
                                            const float* __restrict__ fcw,
                                            unsigned short* __restrict__ xb,
                                            unsigned short* __restrict__ wcT) {
  // Fold LDS: per-h 64x64 bf16 slabs of A=fcw[j][k] and B=wv-as-[m][d], double-buffered.
  // 32 KB total. XOR swizzle (row&7)<<4 on the in-row byte so the stride-128B fragment
  // reads are <=2-way bank aliases (free) instead of 16-way.
  __shared__ __align__(16) short As[2][64 * 64];
  __shared__ __align__(16) short Bs[2][64 * 64];

  int bid = blockIdx.x, t = threadIdx.x;
  int wid = t >> 6, lane = t & 63, l16 = lane & 15, quad = lane >> 4;

  if (bid < 256) {
    // wcT[j][m] = sum_{h,d} fcw[j][h*64+d] * wv[h][m][d]; 64x64 output tile, 4 waves 2x2,
    // each wave a 32x32 sub-tile (2x2 frags of 16x16), K-loop = 16 h-slabs of 64.
    int j0 = (bid >> 4) * 64;   // j tile
    int m0 = (bid & 15) * 64;   // m tile
    int wr = wid >> 1, wc = wid & 1;
    int rowt = t >> 3, colb = (t & 7) * 8;  // staging: chunk c row = c*32+rowt, 8 floats at colb

    f32x4 acc[2][2];
#pragma unroll
    for (int a = 0; a < 2; a++)
#pragma unroll
      for (int b = 0; b < 2; b++) acc[a][b] = (f32x4){0.f, 0.f, 0.f, 0.f};

    float4 ra[2][2], rb[2][2];  // [chunk][2xfloat4] in-flight slab

#define LOADH(h)                                                                     \
    {                                                                                \
      _Pragma("unroll")                                                              \
      for (int c = 0; c < 2; c++) {                                                  \
        int row = c * 32 + rowt;                                                     \
        const float* pa = fcw + (j0 + row) * 1024 + (h) * 64 + colb;                 \
        ra[c][0] = *reinterpret_cast<const float4*>(pa);                             \
        ra[c][1] = *reinterpret_cast<const float4*>(pa + 4);                         \
        const float* pb = wv + (h) * 65536 + (m0 + row) * 64 + colb;                 \
        rb[c][0] = *reinterpret_cast<const float4*>(pb);                             \
        rb[c][1] = *reinterpret_cast<const float4*>(pb + 4);                         \
      }                                                                              \
    }
#define STOREH(buf)                                                                  \
    {                                                                                \
      _Pragma("unroll")                                                              \
      for (int c = 0; c < 2; c++) {                                                  \
        int row = c * 32 + rowt;                                                     \
        int bo = row * 128 + ((colb * 2) ^ ((row & 7) << 4));                        \
        *reinterpret_cast<bf16x8*>((char*)As[buf] + bo) = cvt8(ra[c][0], ra[c][1]);  \
        *reinterpret_cast<bf16x8*>((char*)Bs[buf] + bo) = cvt8(rb[c][0], rb[c][1]);  \
      }                                                                              \
    }

    LOADH(0);
    STOREH(0);
    __syncthreads();

    for (int h = 0; h < 16; ++h) {
      int cur = h & 1;
      if (h < 15) LOADH(h + 1);  // issue-early: HBM latency hides under frag reads + MFMA

      bf16x8 af[2][2], bg[2][2];  // [tile][ks]
#pragma unroll
      for (int rt = 0; rt < 2; rt++) {
        int rowf = wr * 32 + rt * 16 + l16;
        int rbase = rowf * 128, rx = (rowf & 7) << 4;
        af[rt][0] = *reinterpret_cast<const bf16x8*>((char*)As[cur] + rbase + ((quad * 16) ^ rx));
        af[rt][1] = *reinterpret_cast<const bf16x8*>((char*)As[cur] + rbase + ((64 + quad * 16) ^ rx));
      }
#pragma unroll
      for (int ct = 0; ct < 2; ct++) {
        int rowf = wc * 32 + ct * 16 + l16;
        int rbase = rowf * 128, rx = (rowf & 7) << 4;
        bg[ct][0] = *reinterpret_cast<const bf16x8*>((char*)Bs[cur] + rbase + ((quad * 16) ^ rx));
        bg[ct][1] = *reinterpret_cast<const bf16x8*>((char*)Bs[cur] + rbase + ((64 + quad * 16) ^ rx));
      }
#pragma unroll
      for (int ks = 0; ks < 2; ks++)
#pragma unroll
        for (int rt = 0; rt < 2; rt++)
#pragma unroll
          for (int ct = 0; ct < 2; ct++)
            acc[rt][ct] = mfma16(af[rt][ks], bg[ct][ks], acc[rt][ct]);

      if (h < 15) STOREH(cur ^ 1);  // write-late into the other buffer
      __syncthreads();
    }
#undef LOADH
#undef STOREH

#pragma unroll
    for (int rt = 0; rt < 2; rt++)
#pragma unroll
      for (int ct = 0; ct < 2; ct++) {
        int jj = j0 + wr * 32 + rt * 16 + quad * 4;
        int mm = m0 + wc * 32 + ct * 16 + l16;
#pragma unroll
        for (int r = 0; r < 4; r++) wcT[(jj + r) * 1024 + mm] = f2b(acc[rt][ct][r]);
      }
  } else {
    // cast: x fp32 -> bf16. 8.4M elems = 4096 chunks of 2048; 768 blocks grid-stride
    // (~5.3 chunks each) so HBM latency is hidden by TLP (4 blocks/CU overall grid).
    int cb = bid - 256;
    for (int ch = cb; ch < 4096; ch += 768) {
      int idx = ch * 2048 + t * 8;
      float4 a = *reinterpret_cast<const float4*>(x + idx);
      float4 b = *reinterpret_cast<const float4*>(x + idx + 4);
      *reinterpret_cast<bf16x8*>(xb + idx) = cvt8(a, b);
    }
  }
}

// out[i][j] = sum_m xb[i][m]*wcT[j][m] + fcb[j].  M=8192,N=1024,K=1024.
// 128x64 tile, BK=32, 32 K-iters, 1024 blocks N-fastest, 4 blocks/CU.
// Counted-vmcnt 2-deep pipeline, 3 LDS buffers (36KB). Per iter:
//   s_waitcnt vmcnt(3) lgkmcnt(0)  -> my tile-t stage landed (t+1 in flight) AND my
//                                     prev-iter ds_reads complete (closes the WAR on
//                                     the buffer STAGE(t+2) will overwrite)
//   sched_barrier; s_barrier; ""::memory; sched_barrier
//                                  -> fences: no ds_read hoists above the barrier
//                                     (other waves' chunks only guaranteed after it)
//   STAGE(t+2) -> buf[(t+2)%3]; COMPUTE(t) -> 6 ds_read_b128 + 8 MFMA.
// Never vmcnt(0) inside the loop. ONLY gld_lds16 ops enter the vmcnt queue (bias is
// loaded in the epilogue, after the final vmcnt(0) drain).
__global__ __launch_bounds__(256, 4) void final_gemm(const unsigned short* __restrict__ xb,
                                                     const unsigned short* __restrict__ wcT,
                                                     const float* __restrict__ fcb,
                                                     float* __restrict__ out) {
  __shared__ __align__(16) unsigned short As[3][128 * 32];  // 24 KB
  __shared__ __align__(16) unsigned short Bs[3][64 * 32];   // 12 KB
  int t = threadIdx.x, wid = t >> 6, lane = t & 63, l16 = lane & 15, quad = lane >> 4;
  int wr = wid >> 1, wc = wid & 1;
  int row0 = (blockIdx.x >> 4) * 128;   // M tile (64)
  int col0 = (blockIdx.x & 15) * 64;    // N tile (16) — fastest: B stays L2-hot

  // A: 128x32 = 8 chunks of 1KB (16 rows each); wave wid stages chunks wid*2, wid*2+1.
  // B: 64x32 = 4 chunks; wave wid stages chunk wid.
  // Within a chunk: lane l -> row (l>>2), k-quarter (l&3)*8 elems. LDS dest linear lane*16B.
  const unsigned short* Ap[2];
  const unsigned short* Bp;
#pragma unroll
  for (int j = 0; j < 2; j++) {
    int blk = wid * 2 + j;
    int row = blk * 16 + (lane >> 2), kq = lane & 3;
    Ap[j] = xb + (row0 + row) * 1024 + kq * 8;
  }
  {
    int row = wid * 16 + (lane >> 2), kq = lane & 3;
    Bp = wcT + (col0 + row) * 1024 + kq * 8;
  }

#define STAGE(tt, buf)                                                                   \
  {                                                                                      \
    _Pragma("unroll")                                                                    \
    for (int j = 0; j < 2; j++)                                                          \
      gld_lds16(Ap[j] + (tt) * 32, &As[buf][(wid * 2 + j) * 512 + lane * 8]);            \
    gld_lds16(Bp + (tt) * 32, &Bs[buf][wid * 512 + lane * 8]);                           \
  }

#define COMPUTE(buf)                                                                     \
  {                                                                                      \
    bf16x8 af[4], bfr[2];                                                                \
    _Pragma("unroll")                                                                    \
    for (int rt = 0; rt < 4; rt++)                                                       \
      af[rt] = *reinterpret_cast<const bf16x8*>(                                         \
          &As[buf][(wr * 64 + rt * 16 + l16) * 32 + quad * 8]);                          \
    _Pragma("unroll")                                                                    \
    for (int ct = 0; ct < 2; ct++)                                                       \
      bfr[ct] = *reinterpret_cast<const bf16x8*>(                                        \
          &Bs[buf][(wc * 32 + ct * 16 + l16) * 32 + quad * 8]);                          \
    _Pragma("unroll")                                                                    \
    for (int rt = 0; rt < 4; rt++)                                                       \
      _Pragma("unroll")                                                                  \
      for (int ct = 0; ct < 2; ct++)                                                     \
        acc[rt][ct] = mfma16(af[rt], bfr[ct], acc[rt][ct]);                              \
  }

// fence cluster: wait (mem-clobber) -> pin -> barrier -> mem-clobber pin after
#define SYNC_WAIT(WAITSTR)                                                               \
  {                                                                                      \
    asm volatile(WAITSTR ::: "memory");                                                  \
    __builtin_amdgcn_sched_barrier(0);                                                   \
    __builtin_amdgcn_s_barrier();                                                        \
    asm volatile("" ::: "memory");                                                       \
    __builtin_amdgcn_sched_barrier(0);                                                   \
  }

  f32x4 acc[4][2];
#pragma unroll
  for (int rt = 0; rt < 4; rt++)
#pragma unroll
    for (int ct = 0; ct < 2; ct++) acc[rt][ct] = (f32x4){0.f, 0.f, 0.f, 0.f};

  // prologue: tiles 0,1 in flight (vmcnt queue = exactly these 6 loads)
  STAGE(0, 0);
  STAGE(1, 1);

  int cur = 0;          // buf of tile t (tile t lives in buf t%3)
  for (int tk = 0; tk < 30; ++tk) {
    SYNC_WAIT("s_waitcnt vmcnt(3) lgkmcnt(0)");       // tile tk landed; tk+1 in flight
    int nxt = cur + 2; if (nxt >= 3) nxt -= 3;        // buf for tile tk+2 (last read at tk-1)
    STAGE(tk + 2, nxt);
    COMPUTE(cur);
    cur = (cur == 2) ? 0 : cur + 1;
  }
  // tk = 30: wait tile 30 (31 still in flight), no stage
  SYNC_WAIT("s_waitcnt vmcnt(3) lgkmcnt(0)");
  COMPUTE(cur);
  cur = (cur == 2) ? 0 : cur + 1;
  // tk = 31: drain
  SYNC_WAIT("s_waitcnt vmcnt(0) lgkmcnt(0)");
  COMPUTE(cur);

#undef STAGE
#undef COMPUTE
#undef SYNC_WAIT

#pragma unroll
  for (int ct = 0; ct < 2; ct++) {
    int j = col0 + wc * 32 + ct * 16 + l16;
    float bias = fcb[j];  // loaded AFTER the loop's vmcnt(0) drain — queue was pure
#pragma unroll
    for (int rt = 0; rt < 4; rt++) {
      int i0 = row0 + wr * 64 + rt * 16 + quad * 4;
      f32x4 a = acc[rt][ct];
#pragma unroll
      for (int r = 0; r < 4; r++) out[(i0 + r) * 1024 + j] = a[r] + bias;
    }
  }
}

extern "C" void kernel_launch(void* const* d_in, const int* in_sizes, int n_in,
                              void* d_out, int out_size, void* d_ws, size_t ws_size,
                              hipStream_t stream) {
  const float* x   = (const float*)d_in[0];
  // d_in[1] mask, d_in[2] w_q, d_in[3] w_k: dead per reference semantics
  const float* wv  = (const float*)d_in[4];
  const float* fcw = (const float*)d_in[5];
  const float* fcb = (const float*)d_in[6];
  float* out = (float*)d_out;

  char* ws = (char*)d_ws;
  unsigned short* xb  = (unsigned short*)(ws);              // 16 MB (8192x1024 bf16)
  unsigned short* wcT = (unsigned short*)(ws + 16777216);   // 2 MB  (1024x1024 bf16)

  prep<<<1024, 256, 0, stream>>>(x, wv, fcw, xb, wcT);
  final_gemm<<<1024, 256, 0, stream>>>(xb, wcT, fcb, out);
}

// Round 7
// 134.635 us; speedup vs baseline: 1.0913x; 1.0374x over previous
//
#include <hip/hip_runtime.h>
#include <hip/hip_bf16.h>

// Problem: B=4, L=2048, D_MODEL=1024, H=16, D_QKV=64.
// Reference einsum 'bhlk,blhd->blhd' contracts k over logits only; softmax sums to 1,
// so attention output == v and the net reduces to:
//   out = x @ Wc + fc_b,  Wc[m][j] = sum_{hd} w_v[h][m][d] * fc_w[j][hd]
// Two launches:
//   prep: blocks 0-255 fold Wc^T || blocks 256-1023 cast x->bf16.
//   final_gemm: 128x64-tile GEMM, 1024 blocks, 4 blocks/CU.
// History: R0 prep rewrite 151->133.5. R3 dbuf+3blk/CU fgemm: 146.9 (REGRESS).
//   R6 counted-vmcnt BK=32 fgemm: 139.7 (REGRESS, +6.2 vs simple). Both scheduling
//   attacks on fgemm lose to the simple 2-barrier structure + 4-blk/CU TLP.
// Budget model (fits all runs +-1us): ~84us harness fills + prep ~24 + fgemm ~26.
// Round-7: fgemm REVERTED to the round-2 133.5 structure verbatim; ONLY change is the
//   XCD-chunked bijective swizzle (1024 = 8 XCD x 128): XCD k owns M-slabs [8k,8k+8)
//   with all 16 N-sharers co-resident -> per-XCD working set 2MB A + 2MB B fits the
//   4MB L2; A's L3->L2 re-fetch traffic drops ~128MB -> ~16MB. Theory: fgemm's 26us
//   (~660 TF, MfmaUtil low) is L3-BW-bound on A re-fetches, not latency-bound.

typedef __attribute__((ext_vector_type(8))) short bf16x8;
typedef __attribute__((ext_vector_type(4))) float f32x4;

__device__ __forceinline__ f32x4 mfma16(bf16x8 a, bf16x8 b, f32x4 c) {
  return __builtin_amdgcn_mfma_f32_16x16x32_bf16(a, b, c, 0, 0, 0);
}

// fp32 -> bf16 bits, round-to-nearest-even
__device__ __forceinline__ unsigned short f2b(float f) {
  unsigned int u = __builtin_bit_cast(unsigned int, f);
  return (unsigned short)((u + 0x7fffu + ((u >> 16) & 1u)) >> 16);
}

__device__ __forceinline__ bf16x8 cvt8(float4 a, float4 b) {
  bf16x8 r;
  r[0] = (short)f2b(a.x); r[1] = (short)f2b(a.y); r[2] = (short)f2b(a.z); r[3] = (short)f2b(a.w);
  r[4] = (short)f2b(b.x); r[5] = (short)f2b(b.y); r[6] = (short)f2b(b.z); r[7] = (short)f2b(b.w);
  return r;
}

// async global->LDS, 16 B per lane (m97 pattern; LDS dest = wave-uniform base + lane*16)
__device__ __forceinline__ void gld_lds16(const void* g, void* l) {
  __builtin_amdgcn_global_load_lds((const __attribute__((address_space(1))) unsigned int*)g,
                                   (__attribute__((address_space(3))) unsigned int*)l, 16, 0, 0);
}

// prep: blocks 0-255 fold Wc^T; blocks 256-1023 cast x->bf16. No inter-block dependency.
__global__ __launch_bounds__(256) void prep(const float* __restrict__ x,
                                            const float* __restrict__ wv,
                                            const float* __restrict__ fcw,
                                            unsigned short* __restrict__ xb,
                                            unsigned short* __restrict__ wcT) {
  // Fold LDS: per-h 64x64 bf16 slabs of A=fcw[j][k] and B=wv-as-[m][d], double-buffered.
  // 32 KB total. XOR swizzle (row&7)<<4 on the in-row byte so the stride-128B fragment
  // reads are <=2-way bank aliases (free) instead of 16-way.
  __shared__ __align__(16) short As[2][64 * 64];
  __shared__ __align__(16) short Bs[2][64 * 64];

  int bid = blockIdx.x, t = threadIdx.x;
  int wid = t >> 6, lane = t & 63, l16 = lane & 15, quad = lane >> 4;

  if (bid < 256) {
    // wcT[j][m] = sum_{h,d} fcw[j][h*64+d] * wv[h][m][d]; 64x64 output tile, 4 waves 2x2,
    // each wave a 32x32 sub-tile (2x2 frags of 16x16), K-loop = 16 h-slabs of 64.
    int j0 = (bid >> 4) * 64;   // j tile
    int m0 = (bid & 15) * 64;   // m tile
    int wr = wid >> 1, wc = wid & 1;
    int rowt = t >> 3, colb = (t & 7) * 8;  // staging: chunk c row = c*32+rowt, 8 floats at colb

    f32x4 acc[2][2];
#pragma unroll
    for (int a = 0; a < 2; a++)
#pragma unroll
      for (int b = 0; b < 2; b++) acc[a][b] = (f32x4){0.f, 0.f, 0.f, 0.f};

    float4 ra[2][2], rb[2][2];  // [chunk][2xfloat4] in-flight slab

#define LOADH(h)                                                                     \
    {                                                                                \
      _Pragma("unroll")                                                              \
      for (int c = 0; c < 2; c++) {                                                  \
        int row = c * 32 + rowt;                                                     \
        const float* pa = fcw + (j0 + row) * 1024 + (h) * 64 + colb;                 \
        ra[c][0] = *reinterpret_cast<const float4*>(pa);                             \
        ra[c][1] = *reinterpret_cast<const float4*>(pa + 4);                         \
        const float* pb = wv + (h) * 65536 + (m0 + row) * 64 + colb;                 \
        rb[c][0] = *reinterpret_cast<const float4*>(pb);                             \
        rb[c][1] = *reinterpret_cast<const float4*>(pb + 4);                         \
      }                                                                              \
    }
#define STOREH(buf)                                                                  \
    {                                                                                \
      _Pragma("unroll")                                                              \
      for (int c = 0; c < 2; c++) {                                                  \
        int row = c * 32 + rowt;                                                     \
        int bo = row * 128 + ((colb * 2) ^ ((row & 7) << 4));                        \
        *reinterpret_cast<bf16x8*>((char*)As[buf] + bo) = cvt8(ra[c][0], ra[c][1]);  \
        *reinterpret_cast<bf16x8*>((char*)Bs[buf] + bo) = cvt8(rb[c][0], rb[c][1]);  \
      }                                                                              \
    }

    LOADH(0);
    STOREH(0);
    __syncthreads();

    for (int h = 0; h < 16; ++h) {
      int cur = h & 1;
      if (h < 15) LOADH(h + 1);  // issue-early: HBM latency hides under frag reads + MFMA

      bf16x8 af[2][2], bg[2][2];  // [tile][ks]
#pragma unroll
      for (int rt = 0; rt < 2; rt++) {
        int rowf = wr * 32 + rt * 16 + l16;
        int rbase = rowf * 128, rx = (rowf & 7) << 4;
        af[rt][0] = *reinterpret_cast<const bf16x8*>((char*)As[cur] + rbase + ((quad * 16) ^ rx));
        af[rt][1] = *reinterpret_cast<const bf16x8*>((char*)As[cur] + rbase + ((64 + quad * 16) ^ rx));
      }
#pragma unroll
      for (int ct = 0; ct < 2; ct++) {
        int rowf = wc * 32 + ct * 16 + l16;
        int rbase = rowf * 128, rx = (rowf & 7) << 4;
        bg[ct][0] = *reinterpret_cast<const bf16x8*>((char*)Bs[cur] + rbase + ((quad * 16) ^ rx));
        bg[ct][1] = *reinterpret_cast<const bf16x8*>((char*)Bs[cur] + rbase + ((64 + quad * 16) ^ rx));
      }
#pragma unroll
      for (int ks = 0; ks < 2; ks++)
#pragma unroll
        for (int rt = 0; rt < 2; rt++)
#pragma unroll
          for (int ct = 0; ct < 2; ct++)
            acc[rt][ct] = mfma16(af[rt][ks], bg[ct][ks], acc[rt][ct]);

      if (h < 15) STOREH(cur ^ 1);  // write-late into the other buffer
      __syncthreads();
    }
#undef LOADH
#undef STOREH

#pragma unroll
    for (int rt = 0; rt < 2; rt++)
#pragma unroll
      for (int ct = 0; ct < 2; ct++) {
        int jj = j0 + wr * 32 + rt * 16 + quad * 4;
        int mm = m0 + wc * 32 + ct * 16 + l16;
#pragma unroll
        for (int r = 0; r < 4; r++) wcT[(jj + r) * 1024 + mm] = f2b(acc[rt][ct][r]);
      }
  } else {
    // cast: x fp32 -> bf16. 8.4M elems = 4096 chunks of 2048; 768 blocks grid-stride
    // (~5.3 chunks each) so HBM latency is hidden by TLP (4 blocks/CU overall grid).
    int cb = bid - 256;
    for (int ch = cb; ch < 4096; ch += 768) {
      int idx = ch * 2048 + t * 8;
      float4 a = *reinterpret_cast<const float4*>(x + idx);
      float4 b = *reinterpret_cast<const float4*>(x + idx + 4);
      *reinterpret_cast<bf16x8*>(xb + idx) = cvt8(a, b);
    }
  }
}

// out[i][j] = sum_m xb[i][m]*wcT[j][m] + fcb[j].  M=8192,N=1024,K=1024.
// 128x64 tile, BK=64 (two 32-k slabs), 1024 blocks, 4 blocks/CU, 24KB LDS.
// Round-2 structure verbatim (best measured: 133.5 total) + XCD-chunked bijective
// swizzle: XCD k (= blockIdx%8) owns swz range [128k,128k+128) = M-slabs [8k,8k+8)
// with all 16 N-sharers -> per-XCD L2 working set = 2MB A + 2MB B (fits 4MB).
__global__ __launch_bounds__(256, 4) void final_gemm(const unsigned short* __restrict__ xb,
                                                     const unsigned short* __restrict__ wcT,
                                                     const float* __restrict__ fcb,
                                                     float* __restrict__ out) {
  __shared__ __align__(16) unsigned short As[2 * 128 * 32];  // 16 KB  [slab][row][32]
  __shared__ __align__(16) unsigned short Bs[2 * 64 * 32];   //  8 KB
  int t = threadIdx.x, wid = t >> 6, lane = t & 63, l16 = lane & 15, quad = lane >> 4;
  int wr = wid >> 1, wc = wid & 1;
  int swz = (blockIdx.x & 7) * 128 + (blockIdx.x >> 3);  // bijective: 1024 = 8 x 128
  int row0 = (swz >> 4) * 128;   // M tile (64 slabs)
  int col0 = (swz & 15) * 64;    // N tile (16) — fastest within an XCD chunk

  // A staging: 16 x 1KB chunks; blk = wid*4+j: slab blk>>3, rows (blk&7)*16 + lane>>2, kq lane&3.
  // B staging:  8 x 1KB chunks; blk = wid*2+j: slab blk>>2, rows (blk&3)*16 + lane>>2, kq lane&3.
  int w4 = wid * 4, w2 = wid * 2;
  const unsigned short* Ap[4];
  const unsigned short* Bp[2];
#pragma unroll
  for (int j = 0; j < 4; j++) {
    int blk = w4 + j, s = blk >> 3;
    int row = (blk & 7) * 16 + (lane >> 2), kq = lane & 3;
    Ap[j] = xb + (row0 + row) * 1024 + s * 32 + kq * 8;
  }
#pragma unroll
  for (int j = 0; j < 2; j++) {
    int blk = w2 + j, s = blk >> 2;
    int row = (blk & 3) * 16 + (lane >> 2), kq = lane & 3;
    Bp[j] = wcT + (col0 + row) * 1024 + s * 32 + kq * 8;
  }

  f32x4 acc[4][2];
#pragma unroll
  for (int rt = 0; rt < 4; rt++)
#pragma unroll
    for (int ct = 0; ct < 2; ct++) acc[rt][ct] = (f32x4){0.f, 0.f, 0.f, 0.f};

  for (int k0 = 0; k0 < 1024; k0 += 64) {
    __syncthreads();
#pragma unroll
    for (int j = 0; j < 4; j++) gld_lds16(Ap[j] + k0, &As[(w4 + j) * 512 + lane * 8]);
#pragma unroll
    for (int j = 0; j < 2; j++) gld_lds16(Bp[j] + k0, &Bs[(w2 + j) * 512 + lane * 8]);
    __syncthreads();
#pragma unroll
    for (int s = 0; s < 2; s++) {
      bf16x8 af[4], bfr[2];
#pragma unroll
      for (int rt = 0; rt < 4; rt++)
        af[rt] = *reinterpret_cast<const bf16x8*>(&As[s * 4096 + (wr * 64 + rt * 16 + l16) * 32 + quad * 8]);
#pragma unroll
      for (int ct = 0; ct < 2; ct++)
        bfr[ct] = *reinterpret_cast<const bf16x8*>(&Bs[s * 2048 + (wc * 32 + ct * 16 + l16) * 32 + quad * 8]);
#pragma unroll
      for (int rt = 0; rt < 4; rt++)
#pragma unroll
        for (int ct = 0; ct < 2; ct++)
          acc[rt][ct] = mfma16(af[rt], bfr[ct], acc[rt][ct]);
    }
  }

#pragma unroll
  for (int ct = 0; ct < 2; ct++) {
    int j = col0 + wc * 32 + ct * 16 + l16;
    float bias = fcb[j];
#pragma unroll
    for (int rt = 0; rt < 4; rt++) {
      int i0 = row0 + wr * 64 + rt * 16 + quad * 4;
      f32x4 a = acc[rt][ct];
#pragma unroll
      for (int r = 0; r < 4; r++) out[(i0 + r) * 1024 + j] = a[r] + bias;
    }
  }
}

extern "C" void kernel_launch(void* const* d_in, const int* in_sizes, int n_in,
                              void* d_out, int out_size, void* d_ws, size_t ws_size,
                              hipStream_t stream) {
  const float* x   = (const float*)d_in[0];
  // d_in[1] mask, d_in[2] w_q, d_in[3] w_k: dead per reference semantics
  const float* wv  = (const float*)d_in[4];
  const float* fcw = (const float*)d_in[5];
  const float* fcb = (const float*)d_in[6];
  float* out = (float*)d_out;

  char* ws = (char*)d_ws;
  unsigned short* xb  = (unsigned short*)(ws);              // 16 MB (8192x1024 bf16)
  unsigned short* wcT = (unsigned short*)(ws + 16777216);   // 2 MB  (1024x1024 bf16)

  prep<<<1024, 256, 0, stream>>>(x, wv, fcw, xb, wcT);
  final_gemm<<<1024, 256, 0, stream>>>(xb, wcT, fcb, out);
}